// Round 22
// baseline (95.146 us; speedup 1.0000x reference)
//
#include <hip/hip_runtime.h>

#define LN 4096
#define DN 150
#define NT 10          // d padded to 10 x 16 tiles
#define KQ 4096        // full K per gemm block (KSPLIT=1: no partials, no reduce)
#define NSS 16         // super-steps of 256 k
#define CONVBLK 2048

typedef __attribute__((ext_vector_type(8))) short bf16x8;
typedef __attribute__((ext_vector_type(4))) float f32x4;

// round-to-nearest-even fp32 -> bf16 (finite inputs only)
__device__ __forceinline__ unsigned int f2bf(float f) {
    unsigned int u = __builtin_bit_cast(unsigned int, f);
    u = (u + 0x7FFFu + ((u >> 16) & 1u)) >> 16;
    return u & 0xFFFFu;
}

__global__ __launch_bounds__(256) void k_zero(f32x4* __restrict__ p, int n4) {
    int i = blockIdx.x * 256 + threadIdx.x;
    if (i < n4) p[i] = (f32x4){0.f, 0.f, 0.f, 0.f};
}

// standalone transpose (fallback path)
__global__ __launch_bounds__(256) void k_transpose(const float* __restrict__ h,
                                                   unsigned short* __restrict__ Ht) {
    __shared__ float S[64][33];
    const int i0 = blockIdx.x * 64;
    const int d0 = blockIdx.y * 32;
    const int tid = threadIdx.x;
    for (int t = tid; t < 64 * 32; t += 256) {
        int ii = t >> 5, dd = t & 31;
        int d = d0 + dd;
        S[ii][dd] = (d < DN) ? h[(size_t)(i0 + ii) * DN + d] : 0.0f;
    }
    __syncthreads();
    for (int t = tid; t < 32 * 64; t += 256) {
        int dd = t >> 6, ii = t & 63;
        Ht[(size_t)(d0 + dd) * LN + i0 + ii] = (unsigned short)f2bf(S[ii][dd]);
    }
}

// Fused prep: blocks [0,CONVBLK) = pure-stream conv adj->Abf (round-17 proven);
//             blocks [CONVBLK, CONVBLK+320) = h->Ht transpose (64x5 tiling).
__global__ __launch_bounds__(256) void k_prep(const float* __restrict__ adj,
                                              const float* __restrict__ h,
                                              unsigned short* __restrict__ Abf,
                                              unsigned short* __restrict__ Ht) {
    __shared__ float S[64][33];
    const int bx = blockIdx.x;
    const int tid = threadIdx.x;
    if (bx < CONVBLK) {
        const f32x4* src = reinterpret_cast<const f32x4*>(adj);
        unsigned int* dst = reinterpret_cast<unsigned int*>(Abf);
        const int stride = CONVBLK * 256;
        size_t c = (size_t)bx * 256 + tid;
        #pragma unroll 4
        for (int it = 0; it < 16; ++it, c += stride) {
            f32x4 v = src[c];
            dst[c] = f2bf(v.x + v.y) | (f2bf(v.z + v.w) << 16);
        }
    } else {
        const int b = bx - CONVBLK;
        const int i0 = (b & 63) * 64;
        const int d0 = (b >> 6) * 32;
        for (int t = tid; t < 64 * 32; t += 256) {
            int ii = t >> 5, dd = t & 31;
            int d = d0 + dd;
            S[ii][dd] = (d < DN) ? h[(size_t)(i0 + ii) * DN + d] : 0.0f;
        }
        __syncthreads();
        for (int t = tid; t < 32 * 64; t += 256) {
            int dd = t >> 6, ii = t & 63;
            Ht[(size_t)(d0 + dd) * LN + i0 + ii] = (unsigned short)f2bf(S[ii][dd]);
        }
    }
}

// Fused gemms, KSPLIT=1 (full K per block -> direct final store, no partials):
//   z=0 (h_out): out_o[m0+row][d] = sum_k Abf[m0+row][k] * Ht[d][k]  (row staging)
//   z=1 (h_in):  out_i[m0+j][d]   = sum_i Abf[i][m0+j]   * Ht[d][i]  (col staging)
// Grid 128x1x2 = 256 blocks.
__global__ __launch_bounds__(256, 2) void k_gemms(const unsigned short* __restrict__ Abf,
                                                  const unsigned short* __restrict__ Ht,
                                                  float* __restrict__ out_o,
                                                  float* __restrict__ out_i) {
    __shared__ unsigned short At[2][32 * 256];  // [row][256 k] bf16, XOR-swizzled, dbuf
    __shared__ float red[32][160];
    const int which = blockIdx.z;               // 0 = h_out, 1 = h_in
    const int tid  = threadIdx.x;
    const int lane = tid & 63;
    const int wave = tid >> 6;
    const int r16  = lane & 15;
    const int g    = lane >> 4;
    const int m0 = blockIdx.x * 32;
    const int kq = 0;

    f32x4 acc[2][NT];
    #pragma unroll
    for (int mt = 0; mt < 2; ++mt)
        #pragma unroll
        for (int n = 0; n < NT; ++n) acc[mt][n] = (f32x4){0.f, 0.f, 0.f, 0.f};

    // staging state (union of the two variants; only one side used per block)
    bf16x8 sv0, sv1, sv2, sv3;            // which==0: one 32-elem row segment
    unsigned int sv[16];                  // which==1: 16 col-pairs
    const int row_s = tid >> 3;           // which==0 geometry
    const int cb    = (tid & 7) * 32;
    const int iof   = tid >> 4;           // which==1 geometry
    const int jp    = tid & 15;

    auto stage_load = [&](int ss) {
        if (which == 0) {
            const unsigned short* src = Abf + (size_t)(m0 + row_s) * LN + kq + ss * 256 + cb;
            sv0 = *reinterpret_cast<const bf16x8*>(src);
            sv1 = *reinterpret_cast<const bf16x8*>(src + 8);
            sv2 = *reinterpret_cast<const bf16x8*>(src + 16);
            sv3 = *reinterpret_cast<const bf16x8*>(src + 24);
        } else {
            #pragma unroll
            for (int rr = 0; rr < 16; ++rr) {
                int il = rr * 16 + iof;
                sv[rr] = *reinterpret_cast<const unsigned int*>(
                    Abf + (size_t)(kq + ss * 256 + il) * LN + m0 + jp * 2);
            }
        }
    };
    auto stage_write = [&](int buf) {
        if (which == 0) {
            const int swz = (row_s & 15) << 3;
            *reinterpret_cast<bf16x8*>(&At[buf][row_s * 256 + ((cb)      ^ swz)]) = sv0;
            *reinterpret_cast<bf16x8*>(&At[buf][row_s * 256 + ((cb + 8)  ^ swz)]) = sv1;
            *reinterpret_cast<bf16x8*>(&At[buf][row_s * 256 + ((cb + 16) ^ swz)]) = sv2;
            *reinterpret_cast<bf16x8*>(&At[buf][row_s * 256 + ((cb + 24) ^ swz)]) = sv3;
        } else {
            const int jA = jp * 2, jB = jA + 1;
            #pragma unroll
            for (int rr = 0; rr < 16; ++rr) {
                int k = rr * 16 + iof;
                At[buf][jA * 256 + (k ^ ((jA & 15) << 3))] = (unsigned short)(sv[rr] & 0xFFFFu);
                At[buf][jB * 256 + (k ^ ((jB & 15) << 3))] = (unsigned short)(sv[rr] >> 16);
            }
        }
    };
    auto frag = [&](int buf, int mt, int s) {
        int row  = mt * 16 + r16;
        int kloc = wave * 64 + s * 32 + g * 8;
        return *reinterpret_cast<const bf16x8*>(&At[buf][row * 256 + (kloc ^ (r16 << 3))]);
    };
    auto loadB = [&](bf16x8 (&bb)[NT], int ss, int s) {
        int k = kq + ss * 256 + wave * 64 + s * 32 + g * 8;
        #pragma unroll
        for (int n = 0; n < NT; ++n)
            bb[n] = *reinterpret_cast<const bf16x8*>(Ht + (size_t)(n * 16 + r16) * LN + k);
    };

    stage_load(0);
    stage_write(0);
    __syncthreads();
    for (int ss = 0; ss < NSS; ++ss) {
        const int buf = ss & 1;
        if (ss + 1 < NSS) stage_load(ss + 1);
        #pragma unroll
        for (int s = 0; s < 2; ++s) {
            bf16x8 B[NT];
            loadB(B, ss, s);
            bf16x8 a0 = frag(buf, 0, s);
            bf16x8 a1 = frag(buf, 1, s);
            #pragma unroll
            for (int n = 0; n < NT; ++n) {
                acc[0][n] = __builtin_amdgcn_mfma_f32_16x16x32_bf16(a0, B[n], acc[0][n], 0, 0, 0);
                acc[1][n] = __builtin_amdgcn_mfma_f32_16x16x32_bf16(a1, B[n], acc[1][n], 0, 0, 0);
            }
        }
        __syncthreads();
        if (ss + 1 < NSS) stage_write(buf ^ 1);
        __syncthreads();
    }

    for (int w4 = 0; w4 < 4; ++w4) {
        if (wave == w4) {
            #pragma unroll
            for (int mt = 0; mt < 2; ++mt)
                #pragma unroll
                for (int n = 0; n < NT; ++n)
                    #pragma unroll
                    for (int q = 0; q < 4; ++q) {
                        int row = mt * 16 + g * 4 + q;
                        if (w4 == 0) red[row][n * 16 + r16]  = acc[mt][n][q];
                        else         red[row][n * 16 + r16] += acc[mt][n][q];
                    }
        }
        __syncthreads();
    }
    float* dst = (which == 0 ? out_o : out_i);
    for (int t2 = tid; t2 < 32 * DN; t2 += 256) {
        int row = t2 / DN, col = t2 % DN;
        dst[(size_t)(m0 + row) * DN + col] = red[row][col];
    }
}

// ---------------- fallback (small ws): legacy fp32 direct path ----------------
template <int TR>
__global__ __launch_bounds__(256, 2) void k_gemm(const float* __restrict__ adj,
                                                 const unsigned short* __restrict__ Ht,
                                                 float* __restrict__ out) {
    __shared__ unsigned short At[2][32 * 256];
    __shared__ float red[32][160];
    const int tid  = threadIdx.x;
    const int lane = tid & 63;
    const int wave = tid >> 6;
    const int r16  = lane & 15;
    const int g    = lane >> 4;
    const int m0 = blockIdx.x * 32;
    const int kq = blockIdx.y * 1024;
    f32x4 acc[2][NT];
    #pragma unroll
    for (int mt = 0; mt < 2; ++mt)
        #pragma unroll
        for (int n = 0; n < NT; ++n) acc[mt][n] = (f32x4){0.f, 0.f, 0.f, 0.f};
    f32x4 sv[16];
    auto stage_load = [&](int ss) {
        if (TR == 0) {
            const int row = tid >> 7;
            const int kk  = tid & 127;
            #pragma unroll
            for (int rr = 0; rr < 16; ++rr) {
                int rowr = rr * 2 + row;
                sv[rr] = *reinterpret_cast<const f32x4*>(
                    adj + ((size_t)(m0 + rowr) * LN + kq + ss * 256 + 2 * kk) * 2);
            }
        } else {
            const int iof2 = tid >> 4;
            const int jp2  = tid & 15;
            #pragma unroll
            for (int rr = 0; rr < 16; ++rr) {
                int il = rr * 16 + iof2;
                sv[rr] = *reinterpret_cast<const f32x4*>(
                    adj + ((size_t)(kq + ss * 256 + il) * LN + m0 + jp2 * 2) * 2);
            }
        }
    };
    auto stage_write = [&](int buf) {
        if (TR == 0) {
            const int row = tid >> 7;
            const int kk  = tid & 127;
            #pragma unroll
            for (int rr = 0; rr < 16; ++rr) {
                int rowr = rr * 2 + row;
                unsigned int u = f2bf(sv[rr].x + sv[rr].y) | (f2bf(sv[rr].z + sv[rr].w) << 16);
                *reinterpret_cast<unsigned int*>(
                    &At[buf][rowr * 256 + ((2 * kk) ^ ((rowr & 15) << 3))]) = u;
            }
        } else {
            const int iof2 = tid >> 4;
            const int jA = (tid & 15) * 2, jB = jA + 1;
            #pragma unroll
            for (int rr = 0; rr < 16; ++rr) {
                int k = rr * 16 + iof2;
                At[buf][jA * 256 + (k ^ ((jA & 15) << 3))] = (unsigned short)f2bf(sv[rr].x + sv[rr].y);
                At[buf][jB * 256 + (k ^ ((jB & 15) << 3))] = (unsigned short)f2bf(sv[rr].z + sv[rr].w);
            }
        }
    };
    auto frag = [&](int buf, int mt, int s) {
        int row  = mt * 16 + r16;
        int kloc = wave * 64 + s * 32 + g * 8;
        return *reinterpret_cast<const bf16x8*>(&At[buf][row * 256 + (kloc ^ (r16 << 3))]);
    };
    auto loadB = [&](bf16x8 (&bb)[NT], int ss, int s) {
        int k = kq + ss * 256 + wave * 64 + s * 32 + g * 8;
        #pragma unroll
        for (int n = 0; n < NT; ++n)
            bb[n] = *reinterpret_cast<const bf16x8*>(Ht + (size_t)(n * 16 + r16) * LN + k);
    };
    stage_load(0); stage_write(0); __syncthreads();
    for (int ss = 0; ss < 4; ++ss) {
        const int buf = ss & 1;
        if (ss + 1 < 4) stage_load(ss + 1);
        #pragma unroll
        for (int s = 0; s < 2; ++s) {
            bf16x8 B[NT];
            loadB(B, ss, s);
            bf16x8 a0 = frag(buf, 0, s);
            bf16x8 a1 = frag(buf, 1, s);
            #pragma unroll
            for (int n = 0; n < NT; ++n) {
                acc[0][n] = __builtin_amdgcn_mfma_f32_16x16x32_bf16(a0, B[n], acc[0][n], 0, 0, 0);
                acc[1][n] = __builtin_amdgcn_mfma_f32_16x16x32_bf16(a1, B[n], acc[1][n], 0, 0, 0);
            }
        }
        __syncthreads();
        if (ss + 1 < 4) stage_write(buf ^ 1);
        __syncthreads();
    }
    for (int w4 = 0; w4 < 4; ++w4) {
        if (wave == w4) {
            #pragma unroll
            for (int mt = 0; mt < 2; ++mt)
                #pragma unroll
                for (int n = 0; n < NT; ++n)
                    #pragma unroll
                    for (int q = 0; q < 4; ++q) {
                        int row = mt * 16 + g * 4 + q;
                        if (w4 == 0) red[row][n * 16 + r16]  = acc[mt][n][q];
                        else         red[row][n * 16 + r16] += acc[mt][n][q];
                    }
        }
        __syncthreads();
    }
    for (int t2 = tid; t2 < 32 * DN; t2 += 256) {
        int row = t2 / DN, col = t2 % DN;
        atomicAdd(&out[(size_t)(m0 + row) * DN + col], red[row][col]);
    }
}

extern "C" void kernel_launch(void* const* d_in, const int* in_sizes, int n_in,
                              void* d_out, int out_size, void* d_ws, size_t ws_size,
                              hipStream_t stream) {
    const float* adj = (const float*)d_in[0];
    const float* h   = (const float*)d_in[1];
    float* out = (float*)d_out;
    char* ws = (char*)d_ws;

    unsigned short* Ht = (unsigned short*)ws;                        // 1.31 MB @ 0
    const size_t offAbf  = 2u << 20;                                 // bf16 A, 33.55 MB
    const size_t need    = offAbf + (size_t)LN * LN * 2;             // ~35.6 MB

    if (ws_size >= need) {
        unsigned short* Abf = (unsigned short*)(ws + offAbf);
        k_prep<<<CONVBLK + 320, 256, 0, stream>>>(adj, h, Abf, Ht);            // conv + transpose
        // z=0 -> h_out (out + LN*DN); z=1 -> h_in (out); full K per block, direct store
        k_gemms<<<dim3(128, 1, 2), 256, 0, stream>>>(Abf, Ht, out + (size_t)LN * DN, out);
    } else {
        k_transpose<<<dim3(64, 5), 256, 0, stream>>>(h, Ht);
        const int n4 = out_size / 4;
        k_zero<<<(n4 + 255) / 256, 256, 0, stream>>>((f32x4*)out, n4);
        k_gemm<0><<<dim3(128, 4), 256, 0, stream>>>(adj, Ht, out + (size_t)LN * DN);
        k_gemm<1><<<dim3(128, 4), 256, 0, stream>>>(adj, Ht, out);
    }
}

// Round 23
// 86.400 us; speedup vs baseline: 1.1012x; 1.1012x over previous
//
#include <hip/hip_runtime.h>

#define LN 4096
#define DN 150
#define NT 10          // d padded to 10 x 16 tiles
#define KSPLIT 2
#define KQ 2048        // k per gemm block
#define NSS 8          // super-steps of 256 k
#define CONVBLK 2048

typedef __attribute__((ext_vector_type(8))) short bf16x8;
typedef __attribute__((ext_vector_type(4))) float f32x4;

// round-to-nearest-even fp32 -> bf16 (finite inputs only)
__device__ __forceinline__ unsigned int f2bf(float f) {
    unsigned int u = __builtin_bit_cast(unsigned int, f);
    u = (u + 0x7FFFu + ((u >> 16) & 1u)) >> 16;
    return u & 0xFFFFu;
}

__global__ __launch_bounds__(256) void k_zero(f32x4* __restrict__ p, int n4) {
    int i = blockIdx.x * 256 + threadIdx.x;
    if (i < n4) p[i] = (f32x4){0.f, 0.f, 0.f, 0.f};
}

// standalone transpose (fallback path)
__global__ __launch_bounds__(256) void k_transpose(const float* __restrict__ h,
                                                   unsigned short* __restrict__ Ht) {
    __shared__ float S[64][33];
    const int i0 = blockIdx.x * 64;
    const int d0 = blockIdx.y * 32;
    const int tid = threadIdx.x;
    for (int t = tid; t < 64 * 32; t += 256) {
        int ii = t >> 5, dd = t & 31;
        int d = d0 + dd;
        S[ii][dd] = (d < DN) ? h[(size_t)(i0 + ii) * DN + d] : 0.0f;
    }
    __syncthreads();
    for (int t = tid; t < 32 * 64; t += 256) {
        int dd = t >> 6, ii = t & 63;
        Ht[(size_t)(d0 + dd) * LN + i0 + ii] = (unsigned short)f2bf(S[ii][dd]);
    }
}

// Fused prep: blocks [0,CONVBLK) = pure-stream conv adj->Abf (round-17 proven);
//             blocks [CONVBLK, CONVBLK+320) = h->Ht transpose (64x5 tiling).
__global__ __launch_bounds__(256) void k_prep(const float* __restrict__ adj,
                                              const float* __restrict__ h,
                                              unsigned short* __restrict__ Abf,
                                              unsigned short* __restrict__ Ht) {
    __shared__ float S[64][33];
    const int bx = blockIdx.x;
    const int tid = threadIdx.x;
    if (bx < CONVBLK) {
        const f32x4* src = reinterpret_cast<const f32x4*>(adj);
        unsigned int* dst = reinterpret_cast<unsigned int*>(Abf);
        const int stride = CONVBLK * 256;
        size_t c = (size_t)bx * 256 + tid;
        #pragma unroll 4
        for (int it = 0; it < 16; ++it, c += stride) {
            f32x4 v = src[c];
            dst[c] = f2bf(v.x + v.y) | (f2bf(v.z + v.w) << 16);
        }
    } else {
        const int b = bx - CONVBLK;
        const int i0 = (b & 63) * 64;
        const int d0 = (b >> 6) * 32;
        for (int t = tid; t < 64 * 32; t += 256) {
            int ii = t >> 5, dd = t & 31;
            int d = d0 + dd;
            S[ii][dd] = (d < DN) ? h[(size_t)(i0 + ii) * DN + d] : 0.0f;
        }
        __syncthreads();
        for (int t = tid; t < 32 * 64; t += 256) {
            int dd = t >> 6, ii = t & 63;
            Ht[(size_t)(d0 + dd) * LN + i0 + ii] = (unsigned short)f2bf(S[ii][dd]);
        }
    }
}

// out h_in = sum of KSPLIT pIn partials; out h_out = sum of KSPLIT pOut partials.
__global__ __launch_bounds__(256) void k_reduce2(const float* __restrict__ pIn,
                                                 const float* __restrict__ pOut,
                                                 float* __restrict__ out, int n4) {
    int i = blockIdx.x * 256 + threadIdx.x;
    if (i >= n4) return;
    const f32x4* a = reinterpret_cast<const f32x4*>(pIn);
    const f32x4* b = reinterpret_cast<const f32x4*>(pOut);
    f32x4 s0 = a[i], s1 = b[i];
    #pragma unroll
    for (int k = 1; k < KSPLIT; ++k) {
        s0 += a[(size_t)k * n4 + i];
        s1 += b[(size_t)k * n4 + i];
    }
    reinterpret_cast<f32x4*>(out)[i] = s0;             // h_in
    reinterpret_cast<f32x4*>(out)[n4 + i] = s1;        // h_out
}

// Fused gemms (round-17 proven bodies; z selects variant):
//   z=0 (h_out): pOut[by][m0+row][d] = sum_k Abf[m0+row][k] * Ht[d][k]  (row staging)
//   z=1 (h_in):  pIn [by][m0+j][d]   = sum_i Abf[i][m0+j]   * Ht[d][i]  (col staging)
// KSPLIT=2: grid 128x2x2 = 512 blocks = exactly 2/CU, single generation, zero tail.
__global__ __launch_bounds__(256, 2) void k_gemms(const unsigned short* __restrict__ Abf,
                                                  const unsigned short* __restrict__ Ht,
                                                  float* __restrict__ pOut,
                                                  float* __restrict__ pIn) {
    __shared__ unsigned short At[2][32 * 256];  // [row][256 k] bf16, XOR-swizzled, dbuf
    __shared__ float red[32][160];
    const int which = blockIdx.z;               // 0 = h_out, 1 = h_in
    const int tid  = threadIdx.x;
    const int lane = tid & 63;
    const int wave = tid >> 6;
    const int r16  = lane & 15;
    const int g    = lane >> 4;
    const int m0 = blockIdx.x * 32;
    const int kq = blockIdx.y * KQ;

    f32x4 acc[2][NT];
    #pragma unroll
    for (int mt = 0; mt < 2; ++mt)
        #pragma unroll
        for (int n = 0; n < NT; ++n) acc[mt][n] = (f32x4){0.f, 0.f, 0.f, 0.f};

    // staging state (union of the two variants; only one side used per block)
    bf16x8 sv0, sv1, sv2, sv3;            // which==0: one 32-elem row segment
    unsigned int sv[16];                  // which==1: 16 col-pairs
    const int row_s = tid >> 3;           // which==0 geometry
    const int cb    = (tid & 7) * 32;
    const int iof   = tid >> 4;           // which==1 geometry
    const int jp    = tid & 15;

    auto stage_load = [&](int ss) {
        if (which == 0) {
            const unsigned short* src = Abf + (size_t)(m0 + row_s) * LN + kq + ss * 256 + cb;
            sv0 = *reinterpret_cast<const bf16x8*>(src);
            sv1 = *reinterpret_cast<const bf16x8*>(src + 8);
            sv2 = *reinterpret_cast<const bf16x8*>(src + 16);
            sv3 = *reinterpret_cast<const bf16x8*>(src + 24);
        } else {
            #pragma unroll
            for (int rr = 0; rr < 16; ++rr) {
                int il = rr * 16 + iof;
                sv[rr] = *reinterpret_cast<const unsigned int*>(
                    Abf + (size_t)(kq + ss * 256 + il) * LN + m0 + jp * 2);
            }
        }
    };
    auto stage_write = [&](int buf) {
        if (which == 0) {
            const int swz = (row_s & 15) << 3;
            *reinterpret_cast<bf16x8*>(&At[buf][row_s * 256 + ((cb)      ^ swz)]) = sv0;
            *reinterpret_cast<bf16x8*>(&At[buf][row_s * 256 + ((cb + 8)  ^ swz)]) = sv1;
            *reinterpret_cast<bf16x8*>(&At[buf][row_s * 256 + ((cb + 16) ^ swz)]) = sv2;
            *reinterpret_cast<bf16x8*>(&At[buf][row_s * 256 + ((cb + 24) ^ swz)]) = sv3;
        } else {
            const int jA = jp * 2, jB = jA + 1;
            #pragma unroll
            for (int rr = 0; rr < 16; ++rr) {
                int k = rr * 16 + iof;
                At[buf][jA * 256 + (k ^ ((jA & 15) << 3))] = (unsigned short)(sv[rr] & 0xFFFFu);
                At[buf][jB * 256 + (k ^ ((jB & 15) << 3))] = (unsigned short)(sv[rr] >> 16);
            }
        }
    };
    auto frag = [&](int buf, int mt, int s) {
        int row  = mt * 16 + r16;
        int kloc = wave * 64 + s * 32 + g * 8;
        return *reinterpret_cast<const bf16x8*>(&At[buf][row * 256 + (kloc ^ (r16 << 3))]);
    };
    auto loadB = [&](bf16x8 (&bb)[NT], int ss, int s) {
        int k = kq + ss * 256 + wave * 64 + s * 32 + g * 8;
        #pragma unroll
        for (int n = 0; n < NT; ++n)
            bb[n] = *reinterpret_cast<const bf16x8*>(Ht + (size_t)(n * 16 + r16) * LN + k);
    };

    stage_load(0);
    stage_write(0);
    __syncthreads();
    for (int ss = 0; ss < NSS; ++ss) {
        const int buf = ss & 1;
        if (ss + 1 < NSS) stage_load(ss + 1);
        #pragma unroll
        for (int s = 0; s < 2; ++s) {
            bf16x8 B[NT];
            loadB(B, ss, s);
            bf16x8 a0 = frag(buf, 0, s);
            bf16x8 a1 = frag(buf, 1, s);
            #pragma unroll
            for (int n = 0; n < NT; ++n) {
                acc[0][n] = __builtin_amdgcn_mfma_f32_16x16x32_bf16(a0, B[n], acc[0][n], 0, 0, 0);
                acc[1][n] = __builtin_amdgcn_mfma_f32_16x16x32_bf16(a1, B[n], acc[1][n], 0, 0, 0);
            }
        }
        __syncthreads();
        if (ss + 1 < NSS) stage_write(buf ^ 1);
        __syncthreads();
    }

    for (int w4 = 0; w4 < 4; ++w4) {
        if (wave == w4) {
            #pragma unroll
            for (int mt = 0; mt < 2; ++mt)
                #pragma unroll
                for (int n = 0; n < NT; ++n)
                    #pragma unroll
                    for (int q = 0; q < 4; ++q) {
                        int row = mt * 16 + g * 4 + q;
                        if (w4 == 0) red[row][n * 16 + r16]  = acc[mt][n][q];
                        else         red[row][n * 16 + r16] += acc[mt][n][q];
                    }
        }
        __syncthreads();
    }
    float* dst = (which == 0 ? pOut : pIn) + (size_t)blockIdx.y * (LN * DN);
    for (int t2 = tid; t2 < 32 * DN; t2 += 256) {
        int row = t2 / DN, col = t2 % DN;
        dst[(size_t)(m0 + row) * DN + col] = red[row][col];
    }
}

// ---------------- fallback (small ws): legacy fp32 direct path ----------------
template <int TR>
__global__ __launch_bounds__(256, 2) void k_gemm(const float* __restrict__ adj,
                                                 const unsigned short* __restrict__ Ht,
                                                 float* __restrict__ out) {
    __shared__ unsigned short At[2][32 * 256];
    __shared__ float red[32][160];
    const int tid  = threadIdx.x;
    const int lane = tid & 63;
    const int wave = tid >> 6;
    const int r16  = lane & 15;
    const int g    = lane >> 4;
    const int m0 = blockIdx.x * 32;
    const int kq = blockIdx.y * 1024;
    f32x4 acc[2][NT];
    #pragma unroll
    for (int mt = 0; mt < 2; ++mt)
        #pragma unroll
        for (int n = 0; n < NT; ++n) acc[mt][n] = (f32x4){0.f, 0.f, 0.f, 0.f};
    f32x4 sv[16];
    auto stage_load = [&](int ss) {
        if (TR == 0) {
            const int row = tid >> 7;
            const int kk  = tid & 127;
            #pragma unroll
            for (int rr = 0; rr < 16; ++rr) {
                int rowr = rr * 2 + row;
                sv[rr] = *reinterpret_cast<const f32x4*>(
                    adj + ((size_t)(m0 + rowr) * LN + kq + ss * 256 + 2 * kk) * 2);
            }
        } else {
            const int iof2 = tid >> 4;
            const int jp2  = tid & 15;
            #pragma unroll
            for (int rr = 0; rr < 16; ++rr) {
                int il = rr * 16 + iof2;
                sv[rr] = *reinterpret_cast<const f32x4*>(
                    adj + ((size_t)(kq + ss * 256 + il) * LN + m0 + jp2 * 2) * 2);
            }
        }
    };
    auto stage_write = [&](int buf) {
        if (TR == 0) {
            const int row = tid >> 7;
            const int kk  = tid & 127;
            #pragma unroll
            for (int rr = 0; rr < 16; ++rr) {
                int rowr = rr * 2 + row;
                unsigned int u = f2bf(sv[rr].x + sv[rr].y) | (f2bf(sv[rr].z + sv[rr].w) << 16);
                *reinterpret_cast<unsigned int*>(
                    &At[buf][rowr * 256 + ((2 * kk) ^ ((rowr & 15) << 3))]) = u;
            }
        } else {
            const int iof2 = tid >> 4;
            const int jA = (tid & 15) * 2, jB = jA + 1;
            #pragma unroll
            for (int rr = 0; rr < 16; ++rr) {
                int k = rr * 16 + iof2;
                At[buf][jA * 256 + (k ^ ((jA & 15) << 3))] = (unsigned short)f2bf(sv[rr].x + sv[rr].y);
                At[buf][jB * 256 + (k ^ ((jB & 15) << 3))] = (unsigned short)f2bf(sv[rr].z + sv[rr].w);
            }
        }
    };
    auto frag = [&](int buf, int mt, int s) {
        int row  = mt * 16 + r16;
        int kloc = wave * 64 + s * 32 + g * 8;
        return *reinterpret_cast<const bf16x8*>(&At[buf][row * 256 + (kloc ^ (r16 << 3))]);
    };
    auto loadB = [&](bf16x8 (&bb)[NT], int ss, int s) {
        int k = kq + ss * 256 + wave * 64 + s * 32 + g * 8;
        #pragma unroll
        for (int n = 0; n < NT; ++n)
            bb[n] = *reinterpret_cast<const bf16x8*>(Ht + (size_t)(n * 16 + r16) * LN + k);
    };
    stage_load(0); stage_write(0); __syncthreads();
    for (int ss = 0; ss < 4; ++ss) {
        const int buf = ss & 1;
        if (ss + 1 < 4) stage_load(ss + 1);
        #pragma unroll
        for (int s = 0; s < 2; ++s) {
            bf16x8 B[NT];
            loadB(B, ss, s);
            bf16x8 a0 = frag(buf, 0, s);
            bf16x8 a1 = frag(buf, 1, s);
            #pragma unroll
            for (int n = 0; n < NT; ++n) {
                acc[0][n] = __builtin_amdgcn_mfma_f32_16x16x32_bf16(a0, B[n], acc[0][n], 0, 0, 0);
                acc[1][n] = __builtin_amdgcn_mfma_f32_16x16x32_bf16(a1, B[n], acc[1][n], 0, 0, 0);
            }
        }
        __syncthreads();
        if (ss + 1 < 4) stage_write(buf ^ 1);
        __syncthreads();
    }
    for (int w4 = 0; w4 < 4; ++w4) {
        if (wave == w4) {
            #pragma unroll
            for (int mt = 0; mt < 2; ++mt)
                #pragma unroll
                for (int n = 0; n < NT; ++n)
                    #pragma unroll
                    for (int q = 0; q < 4; ++q) {
                        int row = mt * 16 + g * 4 + q;
                        if (w4 == 0) red[row][n * 16 + r16]  = acc[mt][n][q];
                        else         red[row][n * 16 + r16] += acc[mt][n][q];
                    }
        }
        __syncthreads();
    }
    for (int t2 = tid; t2 < 32 * DN; t2 += 256) {
        int row = t2 / DN, col = t2 % DN;
        atomicAdd(&out[(size_t)(m0 + row) * DN + col], red[row][col]);
    }
}

extern "C" void kernel_launch(void* const* d_in, const int* in_sizes, int n_in,
                              void* d_out, int out_size, void* d_ws, size_t ws_size,
                              hipStream_t stream) {
    const float* adj = (const float*)d_in[0];
    const float* h   = (const float*)d_in[1];
    float* out = (float*)d_out;
    char* ws = (char*)d_ws;

    unsigned short* Ht = (unsigned short*)ws;                        // 1.31 MB @ 0
    const size_t offAbf  = 2u << 20;                                 // bf16 A, 33.55 MB
    const size_t psz     = (size_t)KSPLIT * LN * DN * 4;             // 4.92 MB
    const size_t offPin  = offAbf + (size_t)LN * LN * 2;
    const size_t offPout = offPin + psz;
    const size_t need    = offPout + psz;                            // ~45.4 MB

    if (ws_size >= need) {
        unsigned short* Abf = (unsigned short*)(ws + offAbf);
        float* pIn  = (float*)(ws + offPin);
        float* pOut = (float*)(ws + offPout);
        k_prep<<<CONVBLK + 320, 256, 0, stream>>>(adj, h, Abf, Ht);        // conv + transpose
        k_gemms<<<dim3(128, KSPLIT, 2), 256, 0, stream>>>(Abf, Ht, pOut, pIn); // both gemms
        const int n4 = (LN * DN) / 4;
        k_reduce2<<<(n4 + 255) / 256, 256, 0, stream>>>(pIn, pOut, out, n4);
    } else {
        k_transpose<<<dim3(64, 5), 256, 0, stream>>>(h, Ht);
        const int n4 = out_size / 4;
        k_zero<<<(n4 + 255) / 256, 256, 0, stream>>>((f32x4*)out, n4);
        k_gemm<0><<<dim3(128, 4), 256, 0, stream>>>(adj, Ht, out + (size_t)LN * DN);
        k_gemm<1><<<dim3(128, 4), 256, 0, stream>>>(adj, Ht, out);
    }
}